// Round 5
// baseline (320.979 us; speedup 1.0000x reference)
//
#include <hip/hip_runtime.h>
#include <math.h>

#define NROWS 10000
#define FEAT  512
#define NHID  64
#define NCLS  10
#define YT_STRIDE 10240   // 10000 padded (zeros in pad); stored XOR-swizzled
#define KB_PAD 320        // padded K blocks of 32 (for dyn fallback)
#define TK    256         // gemm_adj K-tile (1KB f32 per row per stage instr)
#define NSPLIT 4
#define TILES_PER_SPLIT 10  // 10240 / TK / NSPLIT

typedef __attribute__((ext_vector_type(8))) short short8;
typedef __attribute__((ext_vector_type(4))) float f32x4;

__device__ __forceinline__ short f2bf(float f) {
  union { float f; unsigned u; } v; v.f = f;
  unsigned r = v.u + 0x7fffu + ((v.u >> 16) & 1u);
  return (short)(r >> 16);
}

__device__ __forceinline__ float wsum64(float v) {
#pragma unroll
  for (int off = 32; off > 0; off >>= 1) v += __shfl_xor(v, off, 64);
  return v;
}

// async global->LDS, 16B per lane, LDS dest = wave-uniform base + lane*16.
// global src address IS per-lane.
__device__ __forceinline__ void gload16(const void* g, void* l) {
  __builtin_amdgcn_global_load_lds(
      (const __attribute__((address_space(1))) unsigned int*)g,
      (__attribute__((address_space(3))) unsigned int*)l, 16, 0, 0);
}

// ---------------------------------------------------------------------------
__global__ __launch_bounds__(256) void prep_w(const float* __restrict__ W1,
                                              const float* __restrict__ W2,
                                              unsigned short* __restrict__ Wt1,
                                              unsigned short* __restrict__ Wt2) {
  int i = blockIdx.x * 256 + threadIdx.x;
  if (i >= FEAT * NHID) return;
  int k = i >> 6, h = i & 63;
  Wt1[h * FEAT + k] = (unsigned short)f2bf(W1[i]);
  Wt2[h * FEAT + k] = (unsigned short)f2bf(W2[i]);
}

// ---------------------------------------------------------------------------
// Kernel 1: Yt_b[col][row^sw(col)] = bf16((x @ W_b)[row][col]), sw(c)=(c&7)<<3.
// The XOR pre-swizzle makes gemm_adj's LDS B-tile bank-conflict-free with a
// LINEAR global_load_lds stage (swizzle lives in the storage layout).
// Flat wave-jobs: 625 row-tiles x 2 branches = 1250 independent waves.
__global__ __launch_bounds__(256) void gemm_xw(const float* __restrict__ x,
                                               const unsigned short* __restrict__ Wt1,
                                               const unsigned short* __restrict__ Wt2,
                                               unsigned short* __restrict__ Yt1,
                                               unsigned short* __restrict__ Yt2) {
  const int lane = threadIdx.x & 63;
  const int wave = threadIdx.x >> 6;
  const int job = blockIdx.x * 4 + wave;
  if (job >= 1250) return;                 // no barriers in kernel: safe
  const int br = (job >= 625) ? 1 : 0;
  const int tile = job - 625 * br;
  const unsigned short* Wt = br ? Wt2 : Wt1;
  unsigned short* Yt       = br ? Yt2 : Yt1;
  const int rowbase = tile * 16;
  const int r16 = lane & 15, g = lane >> 4, ga = g * 8;

  const float* arow = x + (size_t)(rowbase + r16) * FEAT + ga;
  const unsigned short* bp = Wt + (size_t)r16 * FEAT + ga;

  f32x4 acc[4];
#pragma unroll
  for (int t = 0; t < 4; ++t) acc[t] = (f32x4){0.f, 0.f, 0.f, 0.f};

#pragma unroll
  for (int kb = 0; kb < FEAT / 32; ++kb) {
    const int k0 = kb * 32;
    const f32x4* ap = (const f32x4*)(arow + k0);
    f32x4 a0 = ap[0], a1 = ap[1];
    short8 af;
    af[0] = f2bf(a0[0]); af[1] = f2bf(a0[1]); af[2] = f2bf(a0[2]); af[3] = f2bf(a0[3]);
    af[4] = f2bf(a1[0]); af[5] = f2bf(a1[1]); af[6] = f2bf(a1[2]); af[7] = f2bf(a1[3]);
#pragma unroll
    for (int t = 0; t < 4; ++t) {
      short8 bf = *(const short8*)(bp + (size_t)t * 16 * FEAT + k0);
      acc[t] = __builtin_amdgcn_mfma_f32_16x16x32_bf16(af, bf, acc[t], 0, 0, 0);
    }
  }
  const int sw = (r16 & 7) << 3;           // col&7 == r16&7 (col = t*16+r16)
#pragma unroll
  for (int t = 0; t < 4; ++t)
#pragma unroll
    for (int rr = 0; rr < 4; ++rr) {
      const int col = t * 16 + r16;
      const int row = rowbase + g * 4 + rr;
      Yt[(size_t)col * YT_STRIDE + (row ^ sw)] = (unsigned short)f2bf(acc[t][rr]);
    }
}

// ---------------------------------------------------------------------------
// Kernel 2 (the hot one): E = adj @ Y.
// Tile: 32 rows x 64 cols x TK=256 k.  A staged ROW-LINEARLY: one gload16 =
// 1KB contiguous of one adj row (DRAM page-friendly).  B staged from the
// pre-swizzled Yt (linear copy -> swizzled LDS).  Ring D=2 with counted
// vmcnt(16): next tile's 16 loads/wave stay in flight across the barrier.
// LDS = 128KB exactly -> 1 block/CU, 4 waves; BW via MLP not occupancy.
__global__ __launch_bounds__(256, 1) void gemm_adj(const float* __restrict__ adj1,
                                                   const float* __restrict__ adj2,
                                                   const unsigned short* __restrict__ Yt1,
                                                   const unsigned short* __restrict__ Yt2,
                                                   float* __restrict__ Ep) {
  __shared__ __attribute__((aligned(16))) float          Asm[2][32 * 256];  // 64KB
  __shared__ __attribute__((aligned(16))) unsigned short Bsm[2][64 * 256];  // 64KB

  const int sp = blockIdx.y;
  const int br = blockIdx.z;
  const float* adj         = br ? adj2 : adj1;
  const unsigned short* Yt = br ? Yt2 : Yt1;
  float* E = Ep + (size_t)(br * NSPLIT + sp) * NROWS * NHID;
  const int k_base = sp * (TILES_PER_SPLIT * TK);
  const int blockrow = blockIdx.x * 32;

  const int lane = threadIdx.x & 63;
  const int wave = threadIdx.x >> 6;

  // staging lane offsets
  const int a_el = lane * 4;               // floats within 256-window
  const int b_cl = lane >> 5;              // 0/1: which of the 2 cols this instr
  const int b_el = (lane & 31) * 8;        // ushorts within 256-window

  // compute indices: wave grid 2x2 -> rows wr*16..+15, cols wc*32..+31
  const int wr = wave >> 1, wc = wave & 1;
  const int r16 = lane & 15, g = lane >> 4;
  const int swb = (r16 & 7) << 3;          // B-frag xor (col&7 == r16&7)

  f32x4 accL = (f32x4){0.f, 0.f, 0.f, 0.f};
  f32x4 accH = accL;

  auto STAGE = [&](int tt) {
    const int k0 = k_base + tt * TK;
    const int bufi = tt & 1;
    // A: this wave stages rows wave*8 .. wave*8+7, 1KB contiguous each
#pragma unroll
    for (int j = 0; j < 8; ++j) {
      const int gr = blockrow + wave * 8 + j;
      const float* src = adj + (size_t)min(gr, NROWS - 1) * NROWS
                             + min(k0 + a_el, NROWS - 4);
      gload16(src, &Asm[bufi][(wave * 8 + j) * 256]);
    }
    // B: this wave stages cols wave*16 .. wave*16+15, 2 cols per instr
#pragma unroll
    for (int j = 0; j < 8; ++j) {
      const int c0 = wave * 16 + j * 2;
      const unsigned short* src =
          Yt + (size_t)(c0 + b_cl) * YT_STRIDE + (k0 + b_el);
      gload16(src, &Bsm[bufi][c0 * 256]);
    }
  };

  auto COMPUTE = [&](int tt) {
    const int bufi = tt & 1;
#pragma unroll
    for (int s = 0; s < 8; ++s) {
      const int kx = s * 32 + g * 8;
      const float* ap = &Asm[bufi][(wr * 16 + r16) * 256 + kx];
      f32x4 a0 = *(const f32x4*)ap;
      f32x4 a1 = *(const f32x4*)(ap + 4);
      const int colL = wc * 32 + r16;
      short8 bL = *(const short8*)&Bsm[bufi][colL * 256 + (kx ^ swb)];
      short8 bH = *(const short8*)&Bsm[bufi][(colL + 16) * 256 + (kx ^ swb)];
      short8 af;
      af[0] = f2bf(a0[0]); af[1] = f2bf(a0[1]); af[2] = f2bf(a0[2]); af[3] = f2bf(a0[3]);
      af[4] = f2bf(a1[0]); af[5] = f2bf(a1[1]); af[6] = f2bf(a1[2]); af[7] = f2bf(a1[3]);
      accL = __builtin_amdgcn_mfma_f32_16x16x32_bf16(af, bL, accL, 0, 0, 0);
      accH = __builtin_amdgcn_mfma_f32_16x16x32_bf16(af, bH, accH, 0, 0, 0);
    }
  };

  STAGE(0);
#pragma unroll 2
  for (int t = 0; t < TILES_PER_SPLIT - 1; ++t) {
    STAGE(t + 1);
    asm volatile("s_waitcnt vmcnt(16)" ::: "memory");  // tile t landed; t+1 flying
    __builtin_amdgcn_sched_barrier(0);
    __builtin_amdgcn_s_barrier();                      // everyone's stage visible
    __builtin_amdgcn_sched_barrier(0);
    COMPUTE(t);
    __builtin_amdgcn_s_barrier();                      // buf t free for reuse
  }
  asm volatile("s_waitcnt vmcnt(0)" ::: "memory");
  __builtin_amdgcn_sched_barrier(0);
  __builtin_amdgcn_s_barrier();
  __builtin_amdgcn_sched_barrier(0);
  COMPUTE(TILES_PER_SPLIT - 1);

  // C layout per MFMA: col = lane&15, row = (lane>>4)*4 + reg
#pragma unroll
  for (int rr = 0; rr < 4; ++rr) {
    const int grow = blockrow + wr * 16 + g * 4 + rr;
    if (grow < NROWS) {
      float* e = E + (size_t)grow * NHID + wc * 32 + r16;
      e[0]  = accL[rr];
      e[16] = accH[rr];
    }
  }
}

// ---------------------------------------------------------------------------
// Fallback (dynamic split) if workspace is tight.  Swizzle-aware B reads.
__global__ __launch_bounds__(256) void gemm_adj_dyn(const float* __restrict__ adj1,
                                                    const float* __restrict__ adj2,
                                                    const unsigned short* __restrict__ Yt1,
                                                    const unsigned short* __restrict__ Yt2,
                                                    float* __restrict__ Ep,
                                                    int nsplit, int chunk) {
  const int sp = blockIdx.y;
  const int br = blockIdx.z;
  const float* adj          = br ? adj2 : adj1;
  const unsigned short* Yt  = br ? Yt2 : Yt1;
  float* E = Ep + (size_t)(br * nsplit + sp) * NROWS * NHID;

  const int kb_begin = sp * chunk;
  const int kb_end   = min(kb_begin + chunk, KB_PAD);

  const int lane = threadIdx.x & 63;
  const int wave = threadIdx.x >> 6;
  const int rowbase = blockIdx.x * 64 + wave * 16;
  if (rowbase >= NROWS) return;
  const int r = lane & 15;
  const int g = lane >> 4;
  const int ga = g * 8;
  const int sw = (r & 7) << 3;

  const float* arow = adj + (size_t)(rowbase + r) * NROWS;

  f32x4 acc0 = (f32x4){0.f, 0.f, 0.f, 0.f};
  f32x4 acc1 = acc0, acc2 = acc0, acc3 = acc0;

#pragma unroll 4
  for (int kb = kb_begin; kb < kb_end; ++kb) {
    const int k0 = kb * 32;
    const int kc = min(k0 + ga, 9992);
    const int ks = (k0 + ga) ^ sw;          // swizzled storage index
    const f32x4* ap = (const f32x4*)(arow + kc);
    f32x4 a0 = ap[0], a1 = ap[1];
    short8 af;
    af[0] = f2bf(a0[0]); af[1] = f2bf(a0[1]); af[2] = f2bf(a0[2]); af[3] = f2bf(a0[3]);
    af[4] = f2bf(a1[0]); af[5] = f2bf(a1[1]); af[6] = f2bf(a1[2]); af[7] = f2bf(a1[3]);
    short8 bf0 = *(const short8*)(Yt + (size_t)(0 * 16 + r) * YT_STRIDE + ks);
    short8 bf1 = *(const short8*)(Yt + (size_t)(1 * 16 + r) * YT_STRIDE + ks);
    short8 bf2 = *(const short8*)(Yt + (size_t)(2 * 16 + r) * YT_STRIDE + ks);
    short8 bf3 = *(const short8*)(Yt + (size_t)(3 * 16 + r) * YT_STRIDE + ks);
    acc0 = __builtin_amdgcn_mfma_f32_16x16x32_bf16(af, bf0, acc0, 0, 0, 0);
    acc1 = __builtin_amdgcn_mfma_f32_16x16x32_bf16(af, bf1, acc1, 0, 0, 0);
    acc2 = __builtin_amdgcn_mfma_f32_16x16x32_bf16(af, bf2, acc2, 0, 0, 0);
    acc3 = __builtin_amdgcn_mfma_f32_16x16x32_bf16(af, bf3, acc3, 0, 0, 0);
  }

  const size_t ebase = (size_t)(rowbase + g * 4) * NHID + r;
#pragma unroll
  for (int rr = 0; rr < 4; ++rr) {
    E[ebase + (size_t)rr * NHID +  0] = acc0[rr];
    E[ebase + (size_t)rr * NHID + 16] = acc1[rr];
    E[ebase + (size_t)rr * NHID + 32] = acc2[rr];
    E[ebase + (size_t)rr * NHID + 48] = acc3[rr];
  }
}

// ---------------------------------------------------------------------------
// Kernel 3: split-K reduction + bias + attention fusion + DEC assignment.
__global__ __launch_bounds__(256) void fuse(const float* __restrict__ Ep,
                                            int nsplit,
                                            const float* __restrict__ b1,
                                            const float* __restrict__ b2,
                                            const float* __restrict__ aw,
                                            const float* __restrict__ cl,
                                            float* __restrict__ out) {
  const int lane = threadIdx.x & 63;
  const int wave = threadIdx.x >> 6;
  const int row = blockIdx.x * 4 + wave;
  if (row >= NROWS) return;

  const size_t off = (size_t)row * NHID + lane;
  const size_t bstride = (size_t)nsplit * NROWS * NHID;
  float e1 = b1[lane], e2 = b2[lane];
  for (int s = 0; s < nsplit; ++s) {
    e1 += Ep[(size_t)s * NROWS * NHID + off];
    e2 += Ep[bstride + (size_t)s * NROWS * NHID + off];
  }

  float a = aw[lane];
  float w1 = wsum64(e1 * a);
  float w2 = wsum64(e2 * a);
  float m = fmaxf(w1, w2);
  float x1 = expf(w1 - m), x2 = expf(w2 - m);
  float inv = 1.0f / (x1 + x2);
  float emb = (x1 * e1 + x2 * e2) * inv;
  out[off] = emb;

  // q_i ~ (1 + d2/alpha)^(-0.72); the *0.5 cancels in normalization
  float myq = 0.f, qs = 0.f;
#pragma unroll
  for (int c = 0; c < NCLS; ++c) {
    float d = emb - cl[c * NHID + lane];
    float s = wsum64(d * d);
    float t = exp2f(-0.72f * log2f(fmaf(5.0f, s, 1.0f)));
    qs += t;
    if (lane == c) myq = t;
  }
  if (lane < NCLS) out[(size_t)NROWS * NHID + (size_t)row * NCLS + lane] = myq / qs;
}

// ---------------------------------------------------------------------------
extern "C" void kernel_launch(void* const* d_in, const int* in_sizes, int n_in,
                              void* d_out, int out_size, void* d_ws, size_t ws_size,
                              hipStream_t stream) {
  const float* x    = (const float*)d_in[0];
  const float* adj1 = (const float*)d_in[1];
  const float* adj2 = (const float*)d_in[2];
  const float* W1   = (const float*)d_in[3];
  const float* b1   = (const float*)d_in[4];
  const float* W2   = (const float*)d_in[5];
  const float* b2   = (const float*)d_in[6];
  const float* aw   = (const float*)d_in[7];
  const float* cl   = (const float*)d_in[8];
  float* out = (float*)d_out;

  char* ws = (char*)d_ws;
  unsigned short* Yt1 = (unsigned short*)(ws + 0);        // 64*10240*2 = 1310720
  unsigned short* Yt2 = (unsigned short*)(ws + 1310720);
  unsigned short* Wt1 = (unsigned short*)(ws + 2621440);  // 64*512*2 = 65536
  unsigned short* Wt2 = (unsigned short*)(ws + 2686976);
  float* Ep           = (float*)(ws + 2752512);

  const size_t fixed = 2752512;
  const size_t per_split = 2ull * NROWS * NHID * 4ull;    // both branches: 5.12 MB
  const bool static_ok = ws_size >= fixed + (size_t)NSPLIT * per_split;

  hipMemsetAsync(Yt1, 0, 2 * 1310720, stream);
  prep_w<<<dim3(128), dim3(256), 0, stream>>>(W1, W2, Wt1, Wt2);
  gemm_xw<<<dim3(313), dim3(256), 0, stream>>>(x, Wt1, Wt2, Yt1, Yt2);

  if (static_ok) {
    gemm_adj<<<dim3(313, NSPLIT, 2), dim3(256), 0, stream>>>(adj1, adj2, Yt1, Yt2, Ep);
    fuse<<<dim3(2500), dim3(256), 0, stream>>>(Ep, NSPLIT, b1, b2, aw, cl, out);
  } else {
    int nsplit = 1;
    if (ws_size > fixed + per_split) {
      size_t s = (ws_size - fixed) / per_split;
      nsplit = (int)(s < 8 ? s : 8);
      if (nsplit < 1) nsplit = 1;
    }
    const int chunk = (KB_PAD + nsplit - 1) / nsplit;
    gemm_adj_dyn<<<dim3(157, nsplit, 2), dim3(256), 0, stream>>>(adj1, adj2, Yt1, Yt2,
                                                                 Ep, nsplit, chunk);
    fuse<<<dim3(2500), dim3(256), 0, stream>>>(Ep, nsplit, b1, b2, aw, cl, out);
  }
}

// Round 6
// 227.979 us; speedup vs baseline: 1.4079x; 1.4079x over previous
//
#include <hip/hip_runtime.h>
#include <math.h>

#define NROWS 10000
#define FEAT  512
#define NHID  64
#define NCLS  10
#define YT_STRIDE 10240   // 10000 padded (zeros in pad); stored XOR-swizzled
#define KB_PAD 320        // padded K blocks of 32 (for dyn fallback)
#define TK    128         // gemm_adj K-tile
#define NSPLIT 4
#define TILES_PER_SPLIT 20  // 10240 / TK / NSPLIT

typedef __attribute__((ext_vector_type(8))) short short8;
typedef __attribute__((ext_vector_type(4))) float f32x4;

__device__ __forceinline__ short f2bf(float f) {
  union { float f; unsigned u; } v; v.f = f;
  unsigned r = v.u + 0x7fffu + ((v.u >> 16) & 1u);
  return (short)(r >> 16);
}

__device__ __forceinline__ float wsum64(float v) {
#pragma unroll
  for (int off = 32; off > 0; off >>= 1) v += __shfl_xor(v, off, 64);
  return v;
}

// async global->LDS, 16B per lane, LDS dest = wave-uniform base + lane*16.
// global src address IS per-lane (enables source-side swizzling).
__device__ __forceinline__ void gload16(const void* g, void* l) {
  __builtin_amdgcn_global_load_lds(
      (const __attribute__((address_space(1))) unsigned int*)g,
      (__attribute__((address_space(3))) unsigned int*)l, 16, 0, 0);
}

// ---------------------------------------------------------------------------
__global__ __launch_bounds__(256) void prep_w(const float* __restrict__ W1,
                                              const float* __restrict__ W2,
                                              unsigned short* __restrict__ Wt1,
                                              unsigned short* __restrict__ Wt2) {
  int i = blockIdx.x * 256 + threadIdx.x;
  if (i >= FEAT * NHID) return;
  int k = i >> 6, h = i & 63;
  Wt1[h * FEAT + k] = (unsigned short)f2bf(W1[i]);
  Wt2[h * FEAT + k] = (unsigned short)f2bf(W2[i]);
}

// ---------------------------------------------------------------------------
// Kernel 1: Yt_b[col][row^sw(col)] = bf16((x @ W_b)[row][col]), sw(c)=(c&7)<<3.
// Storage pre-swizzle cancels against gemm_adj's LDS read swizzle, making the
// B stage a LINEAR global_load_lds copy.  1250 independent waves.
__global__ __launch_bounds__(256) void gemm_xw(const float* __restrict__ x,
                                               const unsigned short* __restrict__ Wt1,
                                               const unsigned short* __restrict__ Wt2,
                                               unsigned short* __restrict__ Yt1,
                                               unsigned short* __restrict__ Yt2) {
  const int lane = threadIdx.x & 63;
  const int wave = threadIdx.x >> 6;
  const int job = blockIdx.x * 4 + wave;
  if (job >= 1250) return;                 // no barriers in kernel: safe
  const int br = (job >= 625) ? 1 : 0;
  const int tile = job - 625 * br;
  const unsigned short* Wt = br ? Wt2 : Wt1;
  unsigned short* Yt       = br ? Yt2 : Yt1;
  const int rowbase = tile * 16;
  const int r16 = lane & 15, g = lane >> 4, ga = g * 8;

  const float* arow = x + (size_t)(rowbase + r16) * FEAT + ga;
  const unsigned short* bp = Wt + (size_t)r16 * FEAT + ga;

  f32x4 acc[4];
#pragma unroll
  for (int t = 0; t < 4; ++t) acc[t] = (f32x4){0.f, 0.f, 0.f, 0.f};

#pragma unroll
  for (int kb = 0; kb < FEAT / 32; ++kb) {
    const int k0 = kb * 32;
    const f32x4* ap = (const f32x4*)(arow + k0);
    f32x4 a0 = ap[0], a1 = ap[1];
    short8 af;
    af[0] = f2bf(a0[0]); af[1] = f2bf(a0[1]); af[2] = f2bf(a0[2]); af[3] = f2bf(a0[3]);
    af[4] = f2bf(a1[0]); af[5] = f2bf(a1[1]); af[6] = f2bf(a1[2]); af[7] = f2bf(a1[3]);
#pragma unroll
    for (int t = 0; t < 4; ++t) {
      short8 bf = *(const short8*)(bp + (size_t)t * 16 * FEAT + k0);
      acc[t] = __builtin_amdgcn_mfma_f32_16x16x32_bf16(af, bf, acc[t], 0, 0, 0);
    }
  }
  const int sw = (r16 & 7) << 3;           // col&7 == r16&7 (col = t*16+r16)
#pragma unroll
  for (int t = 0; t < 4; ++t)
#pragma unroll
    for (int rr = 0; rr < 4; ++rr) {
      const int col = t * 16 + r16;
      const int row = rowbase + g * 4 + rr;
      Yt[(size_t)col * YT_STRIDE + (row ^ sw)] = (unsigned short)f2bf(acc[t][rr]);
    }
}

// ---------------------------------------------------------------------------
// Kernel 2 (the hot one): E = adj @ Y.
// Tile: 32 rows x 64 cols x TK=128.  A staged row-contiguously (512B runs,
// DRAM-page friendly) with BOTH-SIDES XOR swizzle (source-side on the global
// address, matching XOR on the LDS read) -> conflict-free A reads.  B staged
// linearly from pre-swizzled Yt.  Ring D=2, counted vmcnt(8).  LDS 64KB ->
// 2 blocks/CU (8 waves) so barrier drains overlap across blocks.
__global__ __launch_bounds__(256, 2) void gemm_adj(const float* __restrict__ adj1,
                                                   const float* __restrict__ adj2,
                                                   const unsigned short* __restrict__ Yt1,
                                                   const unsigned short* __restrict__ Yt2,
                                                   float* __restrict__ Ep) {
  __shared__ __attribute__((aligned(16))) float          Asm[2][32 * TK];  // 2x16KB
  __shared__ __attribute__((aligned(16))) unsigned short Bsm[2][64 * TK];  // 2x16KB

  const int sp = blockIdx.y;
  const int br = blockIdx.z;
  const float* adj         = br ? adj2 : adj1;
  const unsigned short* Yt = br ? Yt2 : Yt1;
  float* E = Ep + (size_t)(br * NSPLIT + sp) * NROWS * NHID;
  const int k_base = sp * (TILES_PER_SPLIT * TK);
  const int blockrow = blockIdx.x * 32;

  const int lane = threadIdx.x & 63;
  const int wave = threadIdx.x >> 6;

  // ---- A staging (per wave: rows wave*8..+7, 4 instrs x 2 rows) ----
  const int ar_in = wave * 8 + (lane >> 5);          // + 2*j at use
  const int a_lin = (lane & 31) * 4;                 // linear float pos in row
  // ---- B staging (per wave: cols wave*16..+15, 4 instrs x 4 cols) ----
  const int b_cl = lane >> 4;                        // 0..3 col within instr
  const int b_el = (lane & 15) * 8;                  // ushort pos in col

  // ---- compute indices: wave grid 2x2 -> rows wr*16..+15, cols wc*32..+31 ----
  const int wr = wave >> 1, wc = wave & 1;
  const int r16 = lane & 15, g = lane >> 4;
  const int arow_t = wr * 16 + r16;                  // A row in tile
  const int aswz = (arow_t & 7) << 2;                // A read xor (float units)
  const int swb = (r16 & 7) << 3;                    // B read xor (ushort units)

  f32x4 accL = (f32x4){0.f, 0.f, 0.f, 0.f};
  f32x4 accH = accL;

  auto STAGE = [&](int tt) {
    const int k0 = k_base + tt * TK;
    const int bufi = tt & 1;
#pragma unroll
    for (int j = 0; j < 4; ++j) {                    // A: 2 rows per instr
      const int rt = ar_in + 2 * j;                  // row in tile (this lane)
      const int gr = min(blockrow + rt, NROWS - 1);
      const int fsrc = a_lin ^ ((gr & 7) << 2);      // source-side swizzle
      const float* src = adj + (size_t)gr * NROWS + min(k0 + fsrc, NROWS - 4);
      gload16(src, &Asm[bufi][(wave * 8 + 2 * j) * TK]);
    }
#pragma unroll
    for (int j = 0; j < 4; ++j) {                    // B: 4 cols per instr
      const int c0 = wave * 16 + j * 4;
      const unsigned short* src =
          Yt + (size_t)(c0 + b_cl) * YT_STRIDE + (k0 + b_el);  // linear!
      gload16(src, &Bsm[bufi][c0 * TK]);
    }
  };

  auto COMPUTE = [&](int tt) {
    const int bufi = tt & 1;
    const int colL = wc * 32 + r16;
#pragma unroll
    for (int s = 0; s < TK / 32; ++s) {
      const int kx = s * 32 + g * 8;
      const float* abase = &Asm[bufi][arow_t * TK];
      f32x4 a0 = *(const f32x4*)(abase + (kx ^ aswz));
      f32x4 a1 = *(const f32x4*)(abase + ((kx + 4) ^ aswz));
      short8 bL = *(const short8*)&Bsm[bufi][colL * TK + (kx ^ swb)];
      short8 bH = *(const short8*)&Bsm[bufi][(colL + 16) * TK + (kx ^ swb)];
      short8 af;
      af[0] = f2bf(a0[0]); af[1] = f2bf(a0[1]); af[2] = f2bf(a0[2]); af[3] = f2bf(a0[3]);
      af[4] = f2bf(a1[0]); af[5] = f2bf(a1[1]); af[6] = f2bf(a1[2]); af[7] = f2bf(a1[3]);
      accL = __builtin_amdgcn_mfma_f32_16x16x32_bf16(af, bL, accL, 0, 0, 0);
      accH = __builtin_amdgcn_mfma_f32_16x16x32_bf16(af, bH, accH, 0, 0, 0);
    }
  };

  STAGE(0);
#pragma unroll 2
  for (int t = 0; t < TILES_PER_SPLIT - 1; ++t) {
    STAGE(t + 1);
    asm volatile("s_waitcnt vmcnt(8)" ::: "memory");  // tile t landed; t+1 flying
    __builtin_amdgcn_sched_barrier(0);
    __builtin_amdgcn_s_barrier();                     // everyone's stage visible
    __builtin_amdgcn_sched_barrier(0);
    COMPUTE(t);
    __builtin_amdgcn_s_barrier();                     // buf t free for reuse
  }
  asm volatile("s_waitcnt vmcnt(0)" ::: "memory");
  __builtin_amdgcn_sched_barrier(0);
  __builtin_amdgcn_s_barrier();
  __builtin_amdgcn_sched_barrier(0);
  COMPUTE(TILES_PER_SPLIT - 1);

  // C layout per MFMA: col = lane&15, row = (lane>>4)*4 + reg
#pragma unroll
  for (int rr = 0; rr < 4; ++rr) {
    const int grow = blockrow + wr * 16 + g * 4 + rr;
    if (grow < NROWS) {
      float* e = E + (size_t)grow * NHID + wc * 32 + r16;
      e[0]  = accL[rr];
      e[16] = accH[rr];
    }
  }
}

// ---------------------------------------------------------------------------
// Fallback (dynamic split) if workspace is tight.  Swizzle-aware B reads.
__global__ __launch_bounds__(256) void gemm_adj_dyn(const float* __restrict__ adj1,
                                                    const float* __restrict__ adj2,
                                                    const unsigned short* __restrict__ Yt1,
                                                    const unsigned short* __restrict__ Yt2,
                                                    float* __restrict__ Ep,
                                                    int nsplit, int chunk) {
  const int sp = blockIdx.y;
  const int br = blockIdx.z;
  const float* adj          = br ? adj2 : adj1;
  const unsigned short* Yt  = br ? Yt2 : Yt1;
  float* E = Ep + (size_t)(br * nsplit + sp) * NROWS * NHID;

  const int kb_begin = sp * chunk;
  const int kb_end   = min(kb_begin + chunk, KB_PAD);

  const int lane = threadIdx.x & 63;
  const int wave = threadIdx.x >> 6;
  const int rowbase = blockIdx.x * 64 + wave * 16;
  if (rowbase >= NROWS) return;
  const int r = lane & 15;
  const int g = lane >> 4;
  const int ga = g * 8;
  const int sw = (r & 7) << 3;

  const float* arow = adj + (size_t)(rowbase + r) * NROWS;

  f32x4 acc0 = (f32x4){0.f, 0.f, 0.f, 0.f};
  f32x4 acc1 = acc0, acc2 = acc0, acc3 = acc0;

#pragma unroll 4
  for (int kb = kb_begin; kb < kb_end; ++kb) {
    const int k0 = kb * 32;
    const int kc = min(k0 + ga, 9992);
    const int ks = (k0 + ga) ^ sw;          // swizzled storage index
    const f32x4* ap = (const f32x4*)(arow + kc);
    f32x4 a0 = ap[0], a1 = ap[1];
    short8 af;
    af[0] = f2bf(a0[0]); af[1] = f2bf(a0[1]); af[2] = f2bf(a0[2]); af[3] = f2bf(a0[3]);
    af[4] = f2bf(a1[0]); af[5] = f2bf(a1[1]); af[6] = f2bf(a1[2]); af[7] = f2bf(a1[3]);
    short8 bf0 = *(const short8*)(Yt + (size_t)(0 * 16 + r) * YT_STRIDE + ks);
    short8 bf1 = *(const short8*)(Yt + (size_t)(1 * 16 + r) * YT_STRIDE + ks);
    short8 bf2 = *(const short8*)(Yt + (size_t)(2 * 16 + r) * YT_STRIDE + ks);
    short8 bf3 = *(const short8*)(Yt + (size_t)(3 * 16 + r) * YT_STRIDE + ks);
    acc0 = __builtin_amdgcn_mfma_f32_16x16x32_bf16(af, bf0, acc0, 0, 0, 0);
    acc1 = __builtin_amdgcn_mfma_f32_16x16x32_bf16(af, bf1, acc1, 0, 0, 0);
    acc2 = __builtin_amdgcn_mfma_f32_16x16x32_bf16(af, bf2, acc2, 0, 0, 0);
    acc3 = __builtin_amdgcn_mfma_f32_16x16x32_bf16(af, bf3, acc3, 0, 0, 0);
  }

  const size_t ebase = (size_t)(rowbase + g * 4) * NHID + r;
#pragma unroll
  for (int rr = 0; rr < 4; ++rr) {
    E[ebase + (size_t)rr * NHID +  0] = acc0[rr];
    E[ebase + (size_t)rr * NHID + 16] = acc1[rr];
    E[ebase + (size_t)rr * NHID + 32] = acc2[rr];
    E[ebase + (size_t)rr * NHID + 48] = acc3[rr];
  }
}

// ---------------------------------------------------------------------------
// Kernel 3: split-K reduction + bias + attention fusion + DEC assignment.
__global__ __launch_bounds__(256) void fuse(const float* __restrict__ Ep,
                                            int nsplit,
                                            const float* __restrict__ b1,
                                            const float* __restrict__ b2,
                                            const float* __restrict__ aw,
                                            const float* __restrict__ cl,
                                            float* __restrict__ out) {
  const int lane = threadIdx.x & 63;
  const int wave = threadIdx.x >> 6;
  const int row = blockIdx.x * 4 + wave;
  if (row >= NROWS) return;

  const size_t off = (size_t)row * NHID + lane;
  const size_t bstride = (size_t)nsplit * NROWS * NHID;
  float e1 = b1[lane], e2 = b2[lane];
  for (int s = 0; s < nsplit; ++s) {
    e1 += Ep[(size_t)s * NROWS * NHID + off];
    e2 += Ep[bstride + (size_t)s * NROWS * NHID + off];
  }

  float a = aw[lane];
  float w1 = wsum64(e1 * a);
  float w2 = wsum64(e2 * a);
  float m = fmaxf(w1, w2);
  float x1 = expf(w1 - m), x2 = expf(w2 - m);
  float inv = 1.0f / (x1 + x2);
  float emb = (x1 * e1 + x2 * e2) * inv;
  out[off] = emb;

  // q_i ~ (1 + d2/alpha)^(-0.72); the *0.5 cancels in normalization
  float myq = 0.f, qs = 0.f;
#pragma unroll
  for (int c = 0; c < NCLS; ++c) {
    float d = emb - cl[c * NHID + lane];
    float s = wsum64(d * d);
    float t = exp2f(-0.72f * log2f(fmaf(5.0f, s, 1.0f)));
    qs += t;
    if (lane == c) myq = t;
  }
  if (lane < NCLS) out[(size_t)NROWS * NHID + (size_t)row * NCLS + lane] = myq / qs;
}

// ---------------------------------------------------------------------------
extern "C" void kernel_launch(void* const* d_in, const int* in_sizes, int n_in,
                              void* d_out, int out_size, void* d_ws, size_t ws_size,
                              hipStream_t stream) {
  const float* x    = (const float*)d_in[0];
  const float* adj1 = (const float*)d_in[1];
  const float* adj2 = (const float*)d_in[2];
  const float* W1   = (const float*)d_in[3];
  const float* b1   = (const float*)d_in[4];
  const float* W2   = (const float*)d_in[5];
  const float* b2   = (const float*)d_in[6];
  const float* aw   = (const float*)d_in[7];
  const float* cl   = (const float*)d_in[8];
  float* out = (float*)d_out;

  char* ws = (char*)d_ws;
  unsigned short* Yt1 = (unsigned short*)(ws + 0);        // 64*10240*2 = 1310720
  unsigned short* Yt2 = (unsigned short*)(ws + 1310720);
  unsigned short* Wt1 = (unsigned short*)(ws + 2621440);  // 64*512*2 = 65536
  unsigned short* Wt2 = (unsigned short*)(ws + 2686976);
  float* Ep           = (float*)(ws + 2752512);

  const size_t fixed = 2752512;
  const size_t per_split = 2ull * NROWS * NHID * 4ull;    // both branches: 5.12 MB
  const bool static_ok = ws_size >= fixed + (size_t)NSPLIT * per_split;

  hipMemsetAsync(Yt1, 0, 2 * 1310720, stream);
  prep_w<<<dim3(128), dim3(256), 0, stream>>>(W1, W2, Wt1, Wt2);
  gemm_xw<<<dim3(313), dim3(256), 0, stream>>>(x, Wt1, Wt2, Yt1, Yt2);

  if (static_ok) {
    gemm_adj<<<dim3(313, NSPLIT, 2), dim3(256), 0, stream>>>(adj1, adj2, Yt1, Yt2, Ep);
    fuse<<<dim3(2500), dim3(256), 0, stream>>>(Ep, NSPLIT, b1, b2, aw, cl, out);
  } else {
    int nsplit = 1;
    if (ws_size > fixed + per_split) {
      size_t s = (ws_size - fixed) / per_split;
      nsplit = (int)(s < 8 ? s : 8);
      if (nsplit < 1) nsplit = 1;
    }
    const int chunk = (KB_PAD + nsplit - 1) / nsplit;
    gemm_adj_dyn<<<dim3(157, nsplit, 2), dim3(256), 0, stream>>>(adj1, adj2, Yt1, Yt2,
                                                                 Ep, nsplit, chunk);
    fuse<<<dim3(2500), dim3(256), 0, stream>>>(Ep, nsplit, b1, b2, aw, cl, out);
  }
}